// Round 14
// baseline (816.553 us; speedup 1.0000x reference)
//
#include <hip/hip_runtime.h>
#include <cstdint>

#define VV     50257
#define VPAD   50432   // 197 * 256
#define DMODEL 768
#define NLAYER 4
#define DINNER 1536
#define DSTATE 16
#define DCONV  4
#define BATCH  2
#define SEQ    512
#define MROWS  (BATCH*SEQ)   // 1024
#define XZS    ((long)MROWS * 2 * DINNER)   // xz gemm_in partial-slice stride (elements)
#define OPS    ((long)MROWS * DMODEL)       // out-proj partial-slice stride (elements)

typedef unsigned short u16;
typedef __attribute__((ext_vector_type(8))) short bf16x8;
typedef __attribute__((ext_vector_type(4))) float f32x4;

__device__ __forceinline__ u16 f2bf(float f) {
  unsigned u = __float_as_uint(f);
  u += 0x7fffu + ((u >> 16) & 1u);
  return (u16)(u >> 16);
}

__device__ __forceinline__ void async16(const void* g, void* l) {
  auto gp = reinterpret_cast<const __attribute__((address_space(1))) unsigned int*>(
      reinterpret_cast<uintptr_t>(g));
  auto lp = reinterpret_cast<__attribute__((address_space(3))) unsigned int*>(
      reinterpret_cast<uintptr_t>(l));
  __builtin_amdgcn_global_load_lds(gp, lp, 16, 0, 0);
}

// ---------------------------------------------------------------- fused prep
__global__ void prep_kern(const float* __restrict__ emb, const float* __restrict__ W_in,
                          const float* __restrict__ W_out, const int* __restrict__ idx,
                          u16* __restrict__ embbf, u16* __restrict__ winbf,
                          u16* __restrict__ woutbf, float* __restrict__ xf,
                          u16* __restrict__ xbf) {
  const int E4  = VPAD * DMODEL / 4;
  const int W14 = NLAYER * 2 * DINNER * DMODEL / 4;
  const int W24 = NLAYER * DMODEL * DINNER / 4;
  const int X4  = MROWS * DMODEL / 4;
  const int TOT = E4 + W14 + W24 + X4;
  int i = blockIdx.x * blockDim.x + threadIdx.x;
  const int stride = gridDim.x * blockDim.x;
  for (; i < TOT; i += stride) {
    if (i < E4) {
      ushort4 o;
      if (i < VV * DMODEL / 4) {
        float4 v = *(const float4*)(emb + (long)i * 4);
        o.x = f2bf(v.x); o.y = f2bf(v.y); o.z = f2bf(v.z); o.w = f2bf(v.w);
      } else { o.x = 0; o.y = 0; o.z = 0; o.w = 0; }
      *(ushort4*)(embbf + (long)i * 4) = o;
    } else if (i < E4 + W14) {
      const int j = i - E4;
      float4 v = *(const float4*)(W_in + (long)j * 4);
      ushort4 o; o.x = f2bf(v.x); o.y = f2bf(v.y); o.z = f2bf(v.z); o.w = f2bf(v.w);
      *(ushort4*)(winbf + (long)j * 4) = o;
    } else if (i < E4 + W14 + W24) {
      const int j = i - E4 - W14;
      float4 v = *(const float4*)(W_out + (long)j * 4);
      ushort4 o; o.x = f2bf(v.x); o.y = f2bf(v.y); o.z = f2bf(v.z); o.w = f2bf(v.w);
      *(ushort4*)(woutbf + (long)j * 4) = o;
    } else {
      const int j = i - E4 - W14 - W24;
      const int r = j / (DMODEL / 4);
      const int c = (j % (DMODEL / 4)) * 4;
      const int id = idx[r];
      float4 v = *(const float4*)(emb + (long)id * DMODEL + c);
      *(float4*)(xf + (long)r * DMODEL + c) = v;
      ushort4 o; o.x = f2bf(v.x); o.y = f2bf(v.y); o.z = f2bf(v.z); o.w = f2bf(v.w);
      *(ushort4*)(xbf + (long)r * DMODEL + c) = o;
    }
  }
}

// ---------------------------------------------------------------- 128^2 ring-3 GEMM (per-layer)
template<bool GUARDN, bool XSWZ>
__global__ __launch_bounds__(256) void gemm3_kern(
    const u16* __restrict__ A, const u16* __restrict__ B,
    float* __restrict__ C, int M, int N, int K, int lda, int ldb)
{
  __shared__ u16 As[3][128 * 32];
  __shared__ u16 Bs[3][128 * 32];
  int bx, by;
  if (XSWZ) {
    const int nt = gridDim.x >> 3;
    const int t = (blockIdx.x & 7) * nt + (blockIdx.x >> 3);
    bx = t & 7; by = t >> 3;
  } else { bx = blockIdx.x; by = blockIdx.y; }
  const int koff = blockIdx.z * K;
  const long coff = (long)blockIdx.z * M * N;

  const int tid  = threadIdx.x;
  const int wave = tid >> 6;
  const int lane = tid & 63;
  const int wr = wave >> 1, wc = wave & 1;
  const int m0 = bx * 128;
  const int n0 = by * 128;

  const int srow = wave * 32 + (lane >> 2);
  const int sblk = ((lane & 3) ^ ((lane >> 3) & 3)) * 8;

  f32x4 acc[4][4];
#pragma unroll
  for (int i = 0; i < 4; ++i)
#pragma unroll
    for (int j = 0; j < 4; ++j) acc[i][j] = (f32x4){0.f, 0.f, 0.f, 0.f};

  const int arow = wr * 64 + (lane & 15);
  const int brow = wc * 64 + (lane & 15);
  const int sa   = (((lane >> 4) ^ ((lane >> 1) & 3)) << 3);

  const int KT = K / 32;
  auto stage = [&](int kt) {
    const int slot = kt % 3;
    const long kcol = (long)koff + kt * 32;
#pragma unroll
    for (int j = 0; j < 2; ++j) {
      async16(A + (long)(m0 + srow + j * 16) * lda + kcol + sblk,
              (char*)(As[slot]) + (wave * 32 + j * 16) * 64);
      async16(B + (long)(n0 + srow + j * 16) * ldb + kcol + sblk,
              (char*)(Bs[slot]) + (wave * 32 + j * 16) * 64);
    }
  };

  stage(0);
  stage(1);
  for (int t2 = 0; t2 < KT; ++t2) {
    if (t2 + 2 < KT) {
      stage(t2 + 2);
      asm volatile("s_waitcnt vmcnt(8)" ::: "memory");
    } else if (t2 + 2 == KT) {
      asm volatile("s_waitcnt vmcnt(4)" ::: "memory");
    } else {
      asm volatile("s_waitcnt vmcnt(0)" ::: "memory");
    }
    __builtin_amdgcn_s_barrier();
    asm volatile("" ::: "memory");

    const u16* as = As[t2 % 3];
    const u16* bs = Bs[t2 % 3];
    bf16x8 af[4], bv[4];
#pragma unroll
    for (int i = 0; i < 4; ++i) af[i] = *(const bf16x8*)(as + (arow + 16 * i) * 32 + sa);
#pragma unroll
    for (int j = 0; j < 4; ++j) bv[j] = *(const bf16x8*)(bs + (brow + 16 * j) * 32 + sa);

    __builtin_amdgcn_s_setprio(1);
#pragma unroll
    for (int i = 0; i < 4; ++i)
#pragma unroll
      for (int j = 0; j < 4; ++j)
        acc[i][j] = __builtin_amdgcn_mfma_f32_16x16x32_bf16(af[i], bv[j], acc[i][j], 0, 0, 0);
    __builtin_amdgcn_s_setprio(0);

    asm volatile("" ::: "memory");
    __builtin_amdgcn_s_barrier();
    asm volatile("" ::: "memory");
  }

  const int rbase = m0 + wr * 64 + ((lane >> 4) << 2);
  const int cbase = n0 + wc * 64 + (lane & 15);
#pragma unroll
  for (int j = 0; j < 4; ++j) {
    const int col = cbase + j * 16;
    if (GUARDN && col >= N) continue;
#pragma unroll
    for (int i = 0; i < 4; ++i) {
#pragma unroll
      for (int r = 0; r < 4; ++r) {
        const int row = rbase + i * 16 + r;
        C[coff + (long)row * N + col] = acc[i][j][r];
      }
    }
  }
}

// ---------------------------------------------------------------- persistent 256^2 4-phase GEMM (logits)
// 256 blocks; block r owns cnt = 3 + (r<20) CONTIGUOUS tiles starting at 3r+min(r,20).
// Tile u: m0=(u&3)*256, n0=(u>>2)*256 (consecutive tiles share B-panel).
// Next tile's prologue issued after the K-loop (LDS quiescent post-Q11-barrier),
// BEFORE the epilogue stores -> tile transition overlaps store drain.
__global__ __launch_bounds__(512, 2) void gemm8_kern(
    const u16* __restrict__ A, const u16* __restrict__ B,
    float* __restrict__ C, int N, int K, int lda, int ldb)
{
  __shared__ u16 lds[2][2][256 * 64];
  const int tid = threadIdx.x;
  const int wave = tid >> 6;
  const int lane = tid & 63;
  const int wm = wave >> 2, wn = wave & 3;
  const int NT = K / 64;   // 12

  const int r = blockIdx.x;
  const int cnt  = 3 + (r < 20 ? 1 : 0);
  const int base = 3 * r + (r < 20 ? r : 20);

  const int sblk = (((lane & 7) ^ (lane >> 3)) << 3);
  auto stage = [&](int buf, int ab, int half, int kt, int sm0, int sn0) {
    const u16* Mat = ab ? B : A;
    const int ld = ab ? ldb : lda;
    const int tb = ab ? sn0 : sm0;
#pragma unroll
    for (int j = 0; j < 2; ++j) {
      const int rloc = half * 128 + j * 64 + wave * 8;
      async16(Mat + (long)(tb + rloc + (lane >> 3)) * ld + kt * 64 + sblk,
              (char*)&lds[buf][ab][0] + (rloc << 7));
    }
  };

  bf16x8 af[4][2], bl[2][2], bh[2][2];
  const int aq = lane >> 4;
  auto readA = [&](int buf, int half) {
#pragma unroll
    for (int mf = 0; mf < 4; ++mf) {
      const int rr = half * 128 + wm * 64 + mf * 16 + (lane & 15);
#pragma unroll
      for (int ks = 0; ks < 2; ++ks) {
        const int q2 = ks * 4 + aq;
        af[mf][ks] = *(const bf16x8*)(&lds[buf][0][0] + rr * 64 + ((q2 ^ (rr & 7)) << 3));
      }
    }
  };
  auto readB = [&](int buf, int half, bf16x8 (&bf)[2][2]) {
#pragma unroll
    for (int nf = 0; nf < 2; ++nf) {
      const int rr = half * 128 + wn * 32 + nf * 16 + (lane & 15);
#pragma unroll
      for (int ks = 0; ks < 2; ++ks) {
        const int q2 = ks * 4 + aq;
        bf[nf][ks] = *(const bf16x8*)(&lds[buf][1][0] + rr * 64 + ((q2 ^ (rr & 7)) << 3));
      }
    }
  };

  f32x4 acc[8][4];

#define MFMA16(QM, QN, BF)                                                        \
  __builtin_amdgcn_s_setprio(1);                                                  \
  _Pragma("unroll")                                                               \
  for (int mf = 0; mf < 4; ++mf)                                                  \
    _Pragma("unroll")                                                             \
    for (int nf = 0; nf < 2; ++nf)                                                \
      _Pragma("unroll")                                                           \
      for (int ks = 0; ks < 2; ++ks)                                              \
        acc[(QM)*4+mf][(QN)*2+nf] = __builtin_amdgcn_mfma_f32_16x16x32_bf16(      \
            af[mf][ks], BF[nf][ks], acc[(QM)*4+mf][(QN)*2+nf], 0, 0, 0);          \
  __builtin_amdgcn_s_setprio(0);

#define BAR()   asm volatile("" ::: "memory"); __builtin_amdgcn_s_barrier(); asm volatile("" ::: "memory")
#define WAITV(NN) asm volatile("s_waitcnt vmcnt(" #NN ")" ::: "memory"); __builtin_amdgcn_sched_barrier(0)
#define WAITL(NN) asm volatile("s_waitcnt lgkmcnt(" #NN ")" ::: "memory"); __builtin_amdgcn_sched_barrier(0)

#define PROLOGUE(M0, N0)                                                          \
  stage(0, 0, 0, 0, M0, N0); stage(0, 1, 0, 0, M0, N0);                           \
  stage(0, 1, 1, 0, M0, N0); stage(0, 0, 1, 0, M0, N0);                           \
  stage(1, 0, 0, 1, M0, N0); stage(1, 1, 0, 1, M0, N0);                           \
  stage(1, 1, 1, 1, M0, N0);

#define TILE(KTE, BUF, TM0, TN0)                                                  \
  {                                                                               \
    const int kt = (KTE);                                                         \
    if (kt >= NT - 2) { WAITV(0); } else { WAITV(8); }                            \
    BAR();                                                                        \
    readA(BUF, 0);                                                                \
    readB(BUF, 1, bh);                                                            \
    if (kt + 1 < NT) stage(BUF ^ 1, 0, 1, kt + 1, TM0, TN0);                      \
    WAITL(4);                                                                     \
    MFMA16(0, 0, bl);                                                             \
    BAR();                                                                        \
    if (kt + 2 < NT) stage(BUF, 0, 0, kt + 2, TM0, TN0);                          \
    WAITL(0);                                                                     \
    MFMA16(0, 1, bh);                                                             \
    if (kt >= NT - 2) { WAITV(0); } else { WAITV(10); }                           \
    BAR();                                                                        \
    readA(BUF, 1);                                                                \
    if (kt + 2 < NT) stage(BUF, 1, 0, kt + 2, TM0, TN0);                          \
    WAITL(0);                                                                     \
    MFMA16(1, 0, bl);                                                             \
    if (kt >= NT - 2) { WAITV(0); } else { WAITV(8); }                            \
    BAR();                                                                        \
    if (kt + 1 < NT) readB(BUF ^ 1, 0, bl);                                       \
    if (kt + 2 < NT) stage(BUF, 1, 1, kt + 2, TM0, TN0);                          \
    WAITL(4);                                                                     \
    MFMA16(1, 1, bh);                                                             \
  }

  {
    const int u0 = base;
    PROLOGUE((u0 & 3) * 256, (u0 >> 2) * 256);
  }

#pragma unroll 1
  for (int i = 0; i < cnt; ++i) {
    const int u = base + i;
    const int cm0 = (u & 3) * 256;
    const int cn0 = (u >> 2) * 256;

#pragma unroll
    for (int a2 = 0; a2 < 8; ++a2)
#pragma unroll
      for (int b2 = 0; b2 < 4; ++b2) acc[a2][b2] = (f32x4){0.f, 0.f, 0.f, 0.f};

    WAITV(6);
    BAR();
    readB(0, 0, bl);

    for (int kt2 = 0; kt2 < NT; kt2 += 2) {
      TILE(kt2, 0, cm0, cn0);
      TILE(kt2 + 1, 1, cm0, cn0);
    }
    // LDS quiescent (post-Q11 barrier). Issue next tile's prologue before stores.
    if (i + 1 < cnt) {
      const int un = u + 1;
      PROLOGUE((un & 3) * 256, (un >> 2) * 256);
    }

#pragma unroll
    for (int qm = 0; qm < 2; ++qm)
#pragma unroll
      for (int mf = 0; mf < 4; ++mf)
#pragma unroll
        for (int qn = 0; qn < 2; ++qn)
#pragma unroll
          for (int nf = 0; nf < 2; ++nf) {
            const int col = cn0 + qn * 128 + wn * 32 + nf * 16 + (lane & 15);
            if (col >= N) continue;
            const int row0 = cm0 + qm * 128 + wm * 64 + mf * 16 + ((lane >> 4) << 2);
            const f32x4 v = acc[qm * 4 + mf][qn * 2 + nf];
#pragma unroll
            for (int rr2 = 0; rr2 < 4; ++rr2)
              C[(long)(row0 + rr2) * N + col] = v[rr2];
          }
  }
#undef TILE
#undef PROLOGUE
#undef MFMA16
#undef BAR
#undef WAITV
#undef WAITL
}

// ---------------------------------------------------------------- split-K(8) reduce + residual + bf16
__global__ __launch_bounds__(256) void redout_kern(const float* __restrict__ part,
                                                   float* __restrict__ xf,
                                                   u16* __restrict__ xbf) {
  const int i = blockIdx.x * blockDim.x + threadIdx.x;
  if (i >= MROWS * DMODEL / 4) return;
  const int stride4 = MROWS * DMODEL / 4;
  float4 s = ((const float4*)xf)[i];
#pragma unroll
  for (int k = 0; k < 8; ++k) {
    float4 p = ((const float4*)part)[i + k * stride4];
    s.x += p.x; s.y += p.y; s.z += p.z; s.w += p.w;
  }
  ((float4*)xf)[i] = s;
  ushort4 o; o.x = f2bf(s.x); o.y = f2bf(s.y); o.z = f2bf(s.z); o.w = f2bf(s.w);
  ((ushort4*)xbf)[i] = o;
}

// ---------------------------------------------------------------- fused conv+SiLU+xproj+delta
__global__ __launch_bounds__(256) void convxproj_kern(
    const float* __restrict__ xz, const float* __restrict__ cw,
    const float* __restrict__ Wx, const float* __restrict__ wdt,
    const float* __restrict__ bdt,
    float* __restrict__ xs, float* __restrict__ dlt, float* __restrict__ bc)
{
  __shared__ float sx[DINNER];
  __shared__ float sxp[40];
  const int row = blockIdx.x;
  const int t = row & (SEQ - 1);
  const int tid = threadIdx.x;

  for (int c = tid; c < DINNER; c += 256) {
    const float* w = cw + c * DCONV;
    float a = 0.f;
#pragma unroll
    for (int k = 0; k < DCONV; ++k) {
      const int tt = t - (DCONV - 1) + k;
      if (tt >= 0) {
        const long ix = (long)(row - (DCONV - 1) + k) * (2 * DINNER) + c;
        a += w[k] * (xz[ix] + xz[ix + XZS]);
      }
    }
    const float s = a / (1.f + __expf(-a));
    sx[c] = s;
    xs[(long)row * DINNER + c] = s;
  }
  __syncthreads();

  const int wv = tid >> 6, lane = tid & 63;
  for (int e = wv; e < 2 * DSTATE + 1; e += 4) {
    const float* We = Wx + (long)e * DINNER;
    float p = 0.f;
    for (int d = lane; d < DINNER; d += 64) p += sx[d] * We[d];
#pragma unroll
    for (int off = 32; off; off >>= 1) p += __shfl_xor(p, off, 64);
    if (lane == 0) sxp[e] = p;
  }
  __syncthreads();
  const float dtr = sxp[0];
  for (int d = tid; d < DINNER; d += 256) {
    float v = dtr * wdt[d] + bdt[d];
    float sp = (v > 15.f) ? v : log1pf(__expf(v));
    dlt[(long)row * DINNER + d] = sp;
  }
  if (tid < 2 * DSTATE) bc[(long)row * (2 * DSTATE) + tid] = sxp[1 + tid];
}

// ---------------------------------------------------------------- chunked selective scan + gate
__global__ __launch_bounds__(256) void scan_kern(
    const float* __restrict__ dlt, const float* __restrict__ bc,
    const float* __restrict__ xs, const float* __restrict__ xz,
    const float* __restrict__ alog, const float* __restrict__ dpar,
    u16* __restrict__ ybf)
{
  __shared__ float sh_h[32][8][DSTATE];
  __shared__ float sh_s[32][8];
  const int tid = threadIdx.x;
  const int ch = tid & 7, chunk = tid >> 3;
  const int ch_abs = blockIdx.x * 8 + ch;
  const int b = ch_abs / DINNER, d = ch_abs % DINNER;
  float An[DSTATE];
#pragma unroll
  for (int n = 0; n < DSTATE; ++n) An[n] = -__expf(alog[(long)d * DSTATE + n]);
  const int r0 = b * SEQ + chunk * 16;

  float h[DSTATE];
#pragma unroll
  for (int n = 0; n < DSTATE; ++n) h[n] = 0.f;
  float ssum = 0.f;
  for (int s = 0; s < 16; ++s) {
    const int row = r0 + s;
    const float dl = dlt[(long)row * DINNER + d];
    const float xv = xs[(long)row * DINNER + d];
    const float dx = dl * xv;
    const float4* bp = (const float4*)(bc + (long)row * (2 * DSTATE));
    float Bv[DSTATE];
    *(float4*)&Bv[0] = bp[0]; *(float4*)&Bv[4] = bp[1];
    *(float4*)&Bv[8] = bp[2]; *(float4*)&Bv[12] = bp[3];
    ssum += dl;
#pragma unroll
    for (int n = 0; n < DSTATE; ++n) h[n] = __expf(dl * An[n]) * h[n] + dx * Bv[n];
  }
#pragma unroll
  for (int n = 0; n < DSTATE; ++n) sh_h[chunk][ch][n] = h[n];
  sh_s[chunk][ch] = ssum;
  __syncthreads();

  if (tid < 128) {
    const int n2 = tid & 15, ch2 = tid >> 4;
    const int d2 = (blockIdx.x * 8 + ch2) % DINNER;
    const float A2 = -__expf(alog[(long)d2 * DSTATE + n2]);
    float carry = 0.f;
    for (int c = 0; c < 32; ++c) {
      const float hl = sh_h[c][ch2][n2];
      sh_h[c][ch2][n2] = carry;
      carry = __expf(A2 * sh_s[c][ch2]) * carry + hl;
    }
  }
  __syncthreads();

#pragma unroll
  for (int n = 0; n < DSTATE; ++n) h[n] = sh_h[chunk][ch][n];
  const float dp = dpar[d];
  for (int s = 0; s < 16; ++s) {
    const int row = r0 + s;
    const float dl = dlt[(long)row * DINNER + d];
    const float xv = xs[(long)row * DINNER + d];
    const float dx = dl * xv;
    const float4* bp = (const float4*)(bc + (long)row * (2 * DSTATE));
    float Bv[DSTATE], Cv[DSTATE];
    *(float4*)&Bv[0] = bp[0]; *(float4*)&Bv[4] = bp[1];
    *(float4*)&Bv[8] = bp[2]; *(float4*)&Bv[12] = bp[3];
    *(float4*)&Cv[0] = bp[4]; *(float4*)&Cv[4] = bp[5];
    *(float4*)&Cv[8] = bp[6]; *(float4*)&Cv[12] = bp[7];
    float y = 0.f;
#pragma unroll
    for (int n = 0; n < DSTATE; ++n) {
      const float hn = __expf(dl * An[n]) * h[n] + dx * Bv[n];
      h[n] = hn;
      y += Cv[n] * hn;
    }
    y += dp * xv;
    const long zix = (long)row * (2 * DINNER) + DINNER + d;
    const float zz = xz[zix] + xz[zix + XZS];
    const float o = y * (zz / (1.f + __expf(-zz)));
    ybf[(long)row * DINNER + d] = f2bf(o);
  }
}

// ---------------------------------------------------------------- fused last-redout(8) + RMSNorm -> bf16
__global__ __launch_bounds__(256) void rmsfuse_kern(const float* __restrict__ part,
                                                    const float* __restrict__ xf,
                                                    const float* __restrict__ nw,
                                                    u16* __restrict__ xnbf) {
  const int row = blockIdx.x, tid = threadIdx.x;
  float v[3];
  float p = 0.f;
#pragma unroll
  for (int k = 0; k < 3; ++k) {
    const int i = row * DMODEL + tid + k * 256;
    float x = xf[i];
#pragma unroll
    for (int q = 0; q < 8; ++q) x += part[i + q * OPS];
    v[k] = x;
    p += x * x;
  }
#pragma unroll
  for (int off = 32; off; off >>= 1) p += __shfl_xor(p, off, 64);
  __shared__ float red[4];
  __shared__ float s_rms;
  const int wv = tid >> 6, lane = tid & 63;
  if (lane == 0) red[wv] = p;
  __syncthreads();
  if (tid == 0) {
    float tsum = red[0] + red[1] + red[2] + red[3];
    s_rms = rsqrtf(tsum / (float)DMODEL + 1e-5f);
  }
  __syncthreads();
  const float r = s_rms;
#pragma unroll
  for (int k = 0; k < 3; ++k) {
    const int dd = tid + k * 256;
    xnbf[(long)row * DMODEL + dd] = f2bf(v[k] * r * nw[dd]);
  }
}

// ---------------------------------------------------------------- host
extern "C" void kernel_launch(void* const* d_in, const int* in_sizes, int n_in,
                              void* d_out, int out_size, void* d_ws, size_t ws_size,
                              hipStream_t stream)
{
  (void)in_sizes; (void)n_in; (void)out_size; (void)ws_size;
  const int*   idx   = (const int*)  d_in[0];
  const float* emb   = (const float*)d_in[1];
  const float* W_in  = (const float*)d_in[2];
  const float* convw = (const float*)d_in[3];
  const float* W_xp  = (const float*)d_in[4];
  const float* W_dt  = (const float*)d_in[5];
  const float* b_dt  = (const float*)d_in[6];
  const float* a_log = (const float*)d_in[7];
  const float* d_par = (const float*)d_in[8];
  const float* W_out = (const float*)d_in[9];
  const float* normw = (const float*)d_in[10];
  float* out = (float*)d_out;

  char* ws = (char*)d_ws;
  size_t off = 0;
  auto alloc = [&](size_t bytes) -> void* {
    void* p = ws + off;
    off += (bytes + 255) & ~(size_t)255;
    return p;
  };
  u16*   embbf  = (u16*)  alloc((size_t)VPAD * DMODEL * 2);
  u16*   winbf  = (u16*)  alloc((size_t)NLAYER * 2 * DINNER * DMODEL * 2);
  u16*   woutbf = (u16*)  alloc((size_t)NLAYER * DMODEL * DINNER * 2);
  float* xf     = (float*)alloc((size_t)MROWS * DMODEL * 4);
  u16*   xbf    = (u16*)  alloc((size_t)MROWS * DMODEL * 2);
  float* xz     = (float*)alloc((size_t)2 * MROWS * 2 * DINNER * 4);  // gemm_in 2 slices; reused as 8 out-proj slices
  float* xs     = (float*)alloc((size_t)MROWS * DINNER * 4);
  float* dlt    = (float*)alloc((size_t)MROWS * DINNER * 4);
  float* bc     = (float*)alloc((size_t)MROWS * 2 * DSTATE * 4);
  u16*   ybf    = (u16*)  alloc((size_t)MROWS * DINNER * 2);
  u16*   xnbf   = (u16*)  alloc((size_t)MROWS * DMODEL * 2);

  prep_kern<<<3072, 256, 0, stream>>>(emb, W_in, W_out, idx, embbf, winbf, woutbf, xf, xbf);

  for (int l = 0; l < NLAYER; ++l) {
    // xz = x @ W_in^T, split-K x2 (384 blocks; slices xz[0], xz[XZS])
    gemm3_kern<false, true><<<dim3(8 * (2 * DINNER / 128), 1, 2), 256, 0, stream>>>(
        xbf, winbf + (size_t)l * 2 * DINNER * DMODEL, xz,
        MROWS, 2 * DINNER, DMODEL / 2, DMODEL, DMODEL);
    convxproj_kern<<<MROWS, 256, 0, stream>>>(
        xz, convw + (size_t)l * DINNER * DCONV,
        W_xp + (size_t)l * (2 * DSTATE + 1) * DINNER,
        W_dt + (size_t)l * DINNER, b_dt + (size_t)l * DINNER, xs, dlt, bc);
    scan_kern<<<BATCH * DINNER / 8, 256, 0, stream>>>(
        dlt, bc, xs, xz, a_log + (size_t)l * DINNER * DSTATE, d_par + (size_t)l * DINNER, ybf);
    // out-proj split-K x8 (384 blocks): partials into xz (dead after scan)
    gemm3_kern<false, true><<<dim3(8 * (DMODEL / 128), 1, 8), 256, 0, stream>>>(
        ybf, woutbf + (size_t)l * DMODEL * DINNER, xz,
        MROWS, DMODEL, DINNER / 8, DINNER, DINNER);
    if (l < NLAYER - 1)
      redout_kern<<<MROWS * DMODEL / 4 / 256, 256, 0, stream>>>(xz, xf, xbf);
  }
  rmsfuse_kern<<<MROWS, 256, 0, stream>>>(xz, xf, normw, xnbf);
  // logits = xn @ emb^T, persistent 4-phase 256^2 (256 blocks x 3-4 tiles)
  gemm8_kern<<<256, 512, 0, stream>>>(
      xnbf, embbf, out, VV, DMODEL, DMODEL, DMODEL);
}

// Round 15
// 792.336 us; speedup vs baseline: 1.0306x; 1.0306x over previous
//
#include <hip/hip_runtime.h>
#include <cstdint>

#define VV     50257
#define VPAD   50432   // 197 * 256
#define DMODEL 768
#define NLAYER 4
#define DINNER 1536
#define DSTATE 16
#define DCONV  4
#define BATCH  2
#define SEQ    512
#define MROWS  (BATCH*SEQ)   // 1024
#define XZS    ((long)MROWS * 2 * DINNER)   // xz partial-slice stride (elements)

typedef unsigned short u16;
typedef __attribute__((ext_vector_type(8))) short bf16x8;
typedef __attribute__((ext_vector_type(4))) float f32x4;

__device__ __forceinline__ u16 f2bf(float f) {
  unsigned u = __float_as_uint(f);
  u += 0x7fffu + ((u >> 16) & 1u);
  return (u16)(u >> 16);
}

__device__ __forceinline__ void async16(const void* g, void* l) {
  auto gp = reinterpret_cast<const __attribute__((address_space(1))) unsigned int*>(
      reinterpret_cast<uintptr_t>(g));
  auto lp = reinterpret_cast<__attribute__((address_space(3))) unsigned int*>(
      reinterpret_cast<uintptr_t>(l));
  __builtin_amdgcn_global_load_lds(gp, lp, 16, 0, 0);
}

// ---------------------------------------------------------------- fused prep
__global__ void prep_kern(const float* __restrict__ emb, const float* __restrict__ W_in,
                          const float* __restrict__ W_out, const int* __restrict__ idx,
                          u16* __restrict__ embbf, u16* __restrict__ winbf,
                          u16* __restrict__ woutbf, float* __restrict__ xf,
                          u16* __restrict__ xbf) {
  const int E4  = VPAD * DMODEL / 4;
  const int W14 = NLAYER * 2 * DINNER * DMODEL / 4;
  const int W24 = NLAYER * DMODEL * DINNER / 4;
  const int X4  = MROWS * DMODEL / 4;
  const int TOT = E4 + W14 + W24 + X4;
  int i = blockIdx.x * blockDim.x + threadIdx.x;
  const int stride = gridDim.x * blockDim.x;
  for (; i < TOT; i += stride) {
    if (i < E4) {
      ushort4 o;
      if (i < VV * DMODEL / 4) {
        float4 v = *(const float4*)(emb + (long)i * 4);
        o.x = f2bf(v.x); o.y = f2bf(v.y); o.z = f2bf(v.z); o.w = f2bf(v.w);
      } else { o.x = 0; o.y = 0; o.z = 0; o.w = 0; }
      *(ushort4*)(embbf + (long)i * 4) = o;
    } else if (i < E4 + W14) {
      const int j = i - E4;
      float4 v = *(const float4*)(W_in + (long)j * 4);
      ushort4 o; o.x = f2bf(v.x); o.y = f2bf(v.y); o.z = f2bf(v.z); o.w = f2bf(v.w);
      *(ushort4*)(winbf + (long)j * 4) = o;
    } else if (i < E4 + W14 + W24) {
      const int j = i - E4 - W14;
      float4 v = *(const float4*)(W_out + (long)j * 4);
      ushort4 o; o.x = f2bf(v.x); o.y = f2bf(v.y); o.z = f2bf(v.z); o.w = f2bf(v.w);
      *(ushort4*)(woutbf + (long)j * 4) = o;
    } else {
      const int j = i - E4 - W14 - W24;
      const int r = j / (DMODEL / 4);
      const int c = (j % (DMODEL / 4)) * 4;
      const int id = idx[r];
      float4 v = *(const float4*)(emb + (long)id * DMODEL + c);
      *(float4*)(xf + (long)r * DMODEL + c) = v;
      ushort4 o; o.x = f2bf(v.x); o.y = f2bf(v.y); o.z = f2bf(v.z); o.w = f2bf(v.w);
      *(ushort4*)(xbf + (long)r * DMODEL + c) = o;
    }
  }
}

// ---------------------------------------------------------------- 128^2 ring-3 GEMM (per-layer)
// blockIdx.z = split-K slice: A/B col offset z*K, C offset z*M*N.
template<bool GUARDN, bool XSWZ>
__global__ __launch_bounds__(256) void gemm3_kern(
    const u16* __restrict__ A, const u16* __restrict__ B,
    float* __restrict__ C, int M, int N, int K, int lda, int ldb)
{
  __shared__ u16 As[3][128 * 32];
  __shared__ u16 Bs[3][128 * 32];
  int bx, by;
  if (XSWZ) {
    const int nt = gridDim.x >> 3;
    const int t = (blockIdx.x & 7) * nt + (blockIdx.x >> 3);
    bx = t & 7; by = t >> 3;
  } else { bx = blockIdx.x; by = blockIdx.y; }
  const int koff = blockIdx.z * K;
  const long coff = (long)blockIdx.z * M * N;

  const int tid  = threadIdx.x;
  const int wave = tid >> 6;
  const int lane = tid & 63;
  const int wr = wave >> 1, wc = wave & 1;
  const int m0 = bx * 128;
  const int n0 = by * 128;

  const int srow = wave * 32 + (lane >> 2);
  const int sblk = ((lane & 3) ^ ((lane >> 3) & 3)) * 8;

  f32x4 acc[4][4];
#pragma unroll
  for (int i = 0; i < 4; ++i)
#pragma unroll
    for (int j = 0; j < 4; ++j) acc[i][j] = (f32x4){0.f, 0.f, 0.f, 0.f};

  const int arow = wr * 64 + (lane & 15);
  const int brow = wc * 64 + (lane & 15);
  const int sa   = (((lane >> 4) ^ ((lane >> 1) & 3)) << 3);

  const int KT = K / 32;
  auto stage = [&](int kt) {
    const int slot = kt % 3;
    const long kcol = (long)koff + kt * 32;
#pragma unroll
    for (int j = 0; j < 2; ++j) {
      async16(A + (long)(m0 + srow + j * 16) * lda + kcol + sblk,
              (char*)(As[slot]) + (wave * 32 + j * 16) * 64);
      async16(B + (long)(n0 + srow + j * 16) * ldb + kcol + sblk,
              (char*)(Bs[slot]) + (wave * 32 + j * 16) * 64);
    }
  };

  stage(0);
  stage(1);
  for (int t2 = 0; t2 < KT; ++t2) {
    if (t2 + 2 < KT) {
      stage(t2 + 2);
      asm volatile("s_waitcnt vmcnt(8)" ::: "memory");
    } else if (t2 + 2 == KT) {
      asm volatile("s_waitcnt vmcnt(4)" ::: "memory");
    } else {
      asm volatile("s_waitcnt vmcnt(0)" ::: "memory");
    }
    __builtin_amdgcn_s_barrier();
    asm volatile("" ::: "memory");

    const u16* as = As[t2 % 3];
    const u16* bs = Bs[t2 % 3];
    bf16x8 af[4], bv[4];
#pragma unroll
    for (int i = 0; i < 4; ++i) af[i] = *(const bf16x8*)(as + (arow + 16 * i) * 32 + sa);
#pragma unroll
    for (int j = 0; j < 4; ++j) bv[j] = *(const bf16x8*)(bs + (brow + 16 * j) * 32 + sa);

    __builtin_amdgcn_s_setprio(1);
#pragma unroll
    for (int i = 0; i < 4; ++i)
#pragma unroll
      for (int j = 0; j < 4; ++j)
        acc[i][j] = __builtin_amdgcn_mfma_f32_16x16x32_bf16(af[i], bv[j], acc[i][j], 0, 0, 0);
    __builtin_amdgcn_s_setprio(0);

    asm volatile("" ::: "memory");
    __builtin_amdgcn_s_barrier();
    asm volatile("" ::: "memory");
  }

  const int rbase = m0 + wr * 64 + ((lane >> 4) << 2);
  const int cbase = n0 + wc * 64 + (lane & 15);
#pragma unroll
  for (int j = 0; j < 4; ++j) {
    const int col = cbase + j * 16;
    if (GUARDN && col >= N) continue;
#pragma unroll
    for (int i = 0; i < 4; ++i) {
#pragma unroll
      for (int r = 0; r < 4; ++r) {
        const int row = rbase + i * 16 + r;
        C[coff + (long)row * N + col] = acc[i][j][r];
      }
    }
  }
}

// ---------------------------------------------------------------- 256^2 4-phase pipelined GEMM (logits)
__global__ __launch_bounds__(512, 2) void gemm8_kern(
    const u16* __restrict__ A, const u16* __restrict__ B,
    float* __restrict__ C, int N, int K, int lda, int ldb)
{
  __shared__ u16 lds[2][2][256 * 64];
  const int tid = threadIdx.x;
  const int wave = tid >> 6;
  const int lane = tid & 63;
  const int wm = wave >> 2, wn = wave & 3;

  const int nwg = gridDim.x;
  const int q = nwg >> 3, r = nwg & 7;
  const int xcd = blockIdx.x & 7;
  const int t = (xcd < r ? xcd * (q + 1) : r * (q + 1) + (xcd - r) * q) + (blockIdx.x >> 3);
  const int m0 = (t & 3) * 256;
  const int n0 = (t >> 2) * 256;

  const int NT = K / 64;

  const int sblk = (((lane & 7) ^ (lane >> 3)) << 3);
  auto stage = [&](int buf, int ab, int half, int kt) {
    const u16* Mat = ab ? B : A;
    const int ld = ab ? ldb : lda;
    const int tb = ab ? n0 : m0;
#pragma unroll
    for (int j = 0; j < 2; ++j) {
      const int rloc = half * 128 + j * 64 + wave * 8;
      async16(Mat + (long)(tb + rloc + (lane >> 3)) * ld + kt * 64 + sblk,
              (char*)&lds[buf][ab][0] + (rloc << 7));
    }
  };

  bf16x8 af[4][2], bl[2][2], bh[2][2];
  const int aq = lane >> 4;
  auto readA = [&](int buf, int half) {
#pragma unroll
    for (int mf = 0; mf < 4; ++mf) {
      const int rr = half * 128 + wm * 64 + mf * 16 + (lane & 15);
#pragma unroll
      for (int ks = 0; ks < 2; ++ks) {
        const int q2 = ks * 4 + aq;
        af[mf][ks] = *(const bf16x8*)(&lds[buf][0][0] + rr * 64 + ((q2 ^ (rr & 7)) << 3));
      }
    }
  };
  auto readB = [&](int buf, int half, bf16x8 (&bf)[2][2]) {
#pragma unroll
    for (int nf = 0; nf < 2; ++nf) {
      const int rr = half * 128 + wn * 32 + nf * 16 + (lane & 15);
#pragma unroll
      for (int ks = 0; ks < 2; ++ks) {
        const int q2 = ks * 4 + aq;
        bf[nf][ks] = *(const bf16x8*)(&lds[buf][1][0] + rr * 64 + ((q2 ^ (rr & 7)) << 3));
      }
    }
  };

  f32x4 acc[8][4];
#pragma unroll
  for (int i = 0; i < 8; ++i)
#pragma unroll
    for (int j = 0; j < 4; ++j) acc[i][j] = (f32x4){0.f, 0.f, 0.f, 0.f};

#define MFMA16(QM, QN, BF)                                                        \
  __builtin_amdgcn_s_setprio(1);                                                  \
  _Pragma("unroll")                                                               \
  for (int mf = 0; mf < 4; ++mf)                                                  \
    _Pragma("unroll")                                                             \
    for (int nf = 0; nf < 2; ++nf)                                                \
      _Pragma("unroll")                                                           \
      for (int ks = 0; ks < 2; ++ks)                                              \
        acc[(QM)*4+mf][(QN)*2+nf] = __builtin_amdgcn_mfma_f32_16x16x32_bf16(      \
            af[mf][ks], BF[nf][ks], acc[(QM)*4+mf][(QN)*2+nf], 0, 0, 0);          \
  __builtin_amdgcn_s_setprio(0);

#define BAR()   asm volatile("" ::: "memory"); __builtin_amdgcn_s_barrier(); asm volatile("" ::: "memory")
#define WAITV(NN) asm volatile("s_waitcnt vmcnt(" #NN ")" ::: "memory"); __builtin_amdgcn_sched_barrier(0)
#define WAITL(NN) asm volatile("s_waitcnt lgkmcnt(" #NN ")" ::: "memory"); __builtin_amdgcn_sched_barrier(0)

  stage(0, 0, 0, 0); stage(0, 1, 0, 0); stage(0, 1, 1, 0); stage(0, 0, 1, 0);
  stage(1, 0, 0, 1); stage(1, 1, 0, 1); stage(1, 1, 1, 1);
  WAITV(6);
  BAR();
  readB(0, 0, bl);

#define TILE(KTE, BUF)                                                            \
  {                                                                               \
    const int kt = (KTE);                                                         \
    if (kt >= NT - 2) { WAITV(0); } else { WAITV(8); }                            \
    BAR();                                                                        \
    readA(BUF, 0);                                                                \
    readB(BUF, 1, bh);                                                            \
    if (kt + 1 < NT) stage(BUF ^ 1, 0, 1, kt + 1);                                \
    WAITL(4);                                                                     \
    MFMA16(0, 0, bl);                                                             \
    BAR();                                                                        \
    if (kt + 2 < NT) stage(BUF, 0, 0, kt + 2);                                    \
    WAITL(0);                                                                     \
    MFMA16(0, 1, bh);                                                             \
    if (kt >= NT - 2) { WAITV(0); } else { WAITV(10); }                           \
    BAR();                                                                        \
    readA(BUF, 1);                                                                \
    if (kt + 2 < NT) stage(BUF, 1, 0, kt + 2);                                    \
    WAITL(0);                                                                     \
    MFMA16(1, 0, bl);                                                             \
    if (kt >= NT - 2) { WAITV(0); } else { WAITV(8); }                            \
    BAR();                                                                        \
    if (kt + 1 < NT) readB(BUF ^ 1, 0, bl);                                       \
    if (kt + 2 < NT) stage(BUF, 1, 1, kt + 2);                                    \
    WAITL(4);                                                                     \
    MFMA16(1, 1, bh);                                                             \
  }

  for (int kt2 = 0; kt2 < NT; kt2 += 2) {
    TILE(kt2, 0);
    TILE(kt2 + 1, 1);
  }

#pragma unroll
  for (int qm = 0; qm < 2; ++qm)
#pragma unroll
    for (int mf = 0; mf < 4; ++mf)
#pragma unroll
      for (int qn = 0; qn < 2; ++qn)
#pragma unroll
        for (int nf = 0; nf < 2; ++nf) {
          const int col = n0 + qn * 128 + wn * 32 + nf * 16 + (lane & 15);
          if (col >= N) continue;
          const int row0 = m0 + qm * 128 + wm * 64 + mf * 16 + ((lane >> 4) << 2);
          const f32x4 v = acc[qm * 4 + mf][qn * 2 + nf];
#pragma unroll
          for (int rr2 = 0; rr2 < 4; ++rr2)
            C[(long)(row0 + rr2) * N + col] = v[rr2];
        }
#undef TILE
#undef MFMA16
#undef BAR
#undef WAITV
#undef WAITL
}

// ---------------------------------------------------------------- split-K reduce + residual + bf16
__global__ __launch_bounds__(256) void redout_kern(const float* __restrict__ part,
                                                   float* __restrict__ xf,
                                                   u16* __restrict__ xbf) {
  const int i = blockIdx.x * blockDim.x + threadIdx.x;
  if (i >= MROWS * DMODEL / 4) return;
  const int stride4 = MROWS * DMODEL / 4;
  float4 s = ((const float4*)part)[i];
  float4 p1 = ((const float4*)part)[i + stride4];
  float4 p2 = ((const float4*)part)[i + 2 * stride4];
  float4 p3 = ((const float4*)part)[i + 3 * stride4];
  float4 x = ((const float4*)xf)[i];
  s.x += p1.x + p2.x + p3.x + x.x;
  s.y += p1.y + p2.y + p3.y + x.y;
  s.z += p1.z + p2.z + p3.z + x.z;
  s.w += p1.w + p2.w + p3.w + x.w;
  ((float4*)xf)[i] = s;
  ushort4 o; o.x = f2bf(s.x); o.y = f2bf(s.y); o.z = f2bf(s.z); o.w = f2bf(s.w);
  ((ushort4*)xbf)[i] = o;
}

// ---------------------------------------------------------------- fused conv+SiLU+xproj+delta
__global__ __launch_bounds__(256) void convxproj_kern(
    const float* __restrict__ xz, const float* __restrict__ cw,
    const float* __restrict__ Wx, const float* __restrict__ wdt,
    const float* __restrict__ bdt,
    float* __restrict__ xs, float* __restrict__ dlt, float* __restrict__ bc)
{
  __shared__ float sx[DINNER];
  __shared__ float sxp[40];
  const int row = blockIdx.x;
  const int t = row & (SEQ - 1);
  const int tid = threadIdx.x;

  for (int c = tid; c < DINNER; c += 256) {
    const float* w = cw + c * DCONV;
    float a = 0.f;
#pragma unroll
    for (int k = 0; k < DCONV; ++k) {
      const int tt = t - (DCONV - 1) + k;
      if (tt >= 0) {
        const long ix = (long)(row - (DCONV - 1) + k) * (2 * DINNER) + c;
        a += w[k] * (xz[ix] + xz[ix + XZS]);
      }
    }
    const float s = a / (1.f + __expf(-a));
    sx[c] = s;
    xs[(long)row * DINNER + c] = s;
  }
  __syncthreads();

  const int wv = tid >> 6, lane = tid & 63;
  for (int e = wv; e < 2 * DSTATE + 1; e += 4) {
    const float* We = Wx + (long)e * DINNER;
    float p = 0.f;
    for (int d = lane; d < DINNER; d += 64) p += sx[d] * We[d];
#pragma unroll
    for (int off = 32; off; off >>= 1) p += __shfl_xor(p, off, 64);
    if (lane == 0) sxp[e] = p;
  }
  __syncthreads();
  const float dtr = sxp[0];
  for (int d = tid; d < DINNER; d += 256) {
    float v = dtr * wdt[d] + bdt[d];
    float sp = (v > 15.f) ? v : log1pf(__expf(v));
    dlt[(long)row * DINNER + d] = sp;
  }
  if (tid < 2 * DSTATE) bc[(long)row * (2 * DSTATE) + tid] = sxp[1 + tid];
}

// ---------------------------------------------------------------- chunked selective scan + gate
__global__ __launch_bounds__(256) void scan_kern(
    const float* __restrict__ dlt, const float* __restrict__ bc,
    const float* __restrict__ xs, const float* __restrict__ xz,
    const float* __restrict__ alog, const float* __restrict__ dpar,
    u16* __restrict__ ybf)
{
  __shared__ float sh_h[32][8][DSTATE];
  __shared__ float sh_s[32][8];
  const int tid = threadIdx.x;
  const int ch = tid & 7, chunk = tid >> 3;
  const int ch_abs = blockIdx.x * 8 + ch;
  const int b = ch_abs / DINNER, d = ch_abs % DINNER;
  float An[DSTATE];
#pragma unroll
  for (int n = 0; n < DSTATE; ++n) An[n] = -__expf(alog[(long)d * DSTATE + n]);
  const int r0 = b * SEQ + chunk * 16;

  float h[DSTATE];
#pragma unroll
  for (int n = 0; n < DSTATE; ++n) h[n] = 0.f;
  float ssum = 0.f;
  for (int s = 0; s < 16; ++s) {
    const int row = r0 + s;
    const float dl = dlt[(long)row * DINNER + d];
    const float xv = xs[(long)row * DINNER + d];
    const float dx = dl * xv;
    const float4* bp = (const float4*)(bc + (long)row * (2 * DSTATE));
    float Bv[DSTATE];
    *(float4*)&Bv[0] = bp[0]; *(float4*)&Bv[4] = bp[1];
    *(float4*)&Bv[8] = bp[2]; *(float4*)&Bv[12] = bp[3];
    ssum += dl;
#pragma unroll
    for (int n = 0; n < DSTATE; ++n) h[n] = __expf(dl * An[n]) * h[n] + dx * Bv[n];
  }
#pragma unroll
  for (int n = 0; n < DSTATE; ++n) sh_h[chunk][ch][n] = h[n];
  sh_s[chunk][ch] = ssum;
  __syncthreads();

  if (tid < 128) {
    const int n2 = tid & 15, ch2 = tid >> 4;
    const int d2 = (blockIdx.x * 8 + ch2) % DINNER;
    const float A2 = -__expf(alog[(long)d2 * DSTATE + n2]);
    float carry = 0.f;
    for (int c = 0; c < 32; ++c) {
      const float hl = sh_h[c][ch2][n2];
      sh_h[c][ch2][n2] = carry;
      carry = __expf(A2 * sh_s[c][ch2]) * carry + hl;
    }
  }
  __syncthreads();

#pragma unroll
  for (int n = 0; n < DSTATE; ++n) h[n] = sh_h[chunk][ch][n];
  const float dp = dpar[d];
  for (int s = 0; s < 16; ++s) {
    const int row = r0 + s;
    const float dl = dlt[(long)row * DINNER + d];
    const float xv = xs[(long)row * DINNER + d];
    const float dx = dl * xv;
    const float4* bp = (const float4*)(bc + (long)row * (2 * DSTATE));
    float Bv[DSTATE], Cv[DSTATE];
    *(float4*)&Bv[0] = bp[0]; *(float4*)&Bv[4] = bp[1];
    *(float4*)&Bv[8] = bp[2]; *(float4*)&Bv[12] = bp[3];
    *(float4*)&Cv[0] = bp[4]; *(float4*)&Cv[4] = bp[5];
    *(float4*)&Cv[8] = bp[6]; *(float4*)&Cv[12] = bp[7];
    float y = 0.f;
#pragma unroll
    for (int n = 0; n < DSTATE; ++n) {
      const float hn = __expf(dl * An[n]) * h[n] + dx * Bv[n];
      h[n] = hn;
      y += Cv[n] * hn;
    }
    y += dp * xv;
    const long zix = (long)row * (2 * DINNER) + DINNER + d;
    const float zz = xz[zix] + xz[zix + XZS];
    const float o = y * (zz / (1.f + __expf(-zz)));
    ybf[(long)row * DINNER + d] = f2bf(o);
  }
}

// ---------------------------------------------------------------- fused last-redout + RMSNorm -> bf16
__global__ __launch_bounds__(256) void rmsfuse_kern(const float* __restrict__ part,
                                                    const float* __restrict__ xf,
                                                    const float* __restrict__ nw,
                                                    u16* __restrict__ xnbf) {
  const int row = blockIdx.x, tid = threadIdx.x;
  const int S = MROWS * DMODEL;
  float v[3];
  float p = 0.f;
#pragma unroll
  for (int k = 0; k < 3; ++k) {
    const int i = row * DMODEL + tid + k * 256;
    float x = xf[i] + part[i] + part[i + S] + part[i + 2 * S] + part[i + 3 * S];
    v[k] = x;
    p += x * x;
  }
#pragma unroll
  for (int off = 32; off; off >>= 1) p += __shfl_xor(p, off, 64);
  __shared__ float red[4];
  __shared__ float s_rms;
  const int wv = tid >> 6, lane = tid & 63;
  if (lane == 0) red[wv] = p;
  __syncthreads();
  if (tid == 0) {
    float tsum = red[0] + red[1] + red[2] + red[3];
    s_rms = rsqrtf(tsum / (float)DMODEL + 1e-5f);
  }
  __syncthreads();
  const float r = s_rms;
#pragma unroll
  for (int k = 0; k < 3; ++k) {
    const int dd = tid + k * 256;
    xnbf[(long)row * DMODEL + dd] = f2bf(v[k] * r * nw[dd]);
  }
}

// ---------------------------------------------------------------- host
extern "C" void kernel_launch(void* const* d_in, const int* in_sizes, int n_in,
                              void* d_out, int out_size, void* d_ws, size_t ws_size,
                              hipStream_t stream)
{
  (void)in_sizes; (void)n_in; (void)out_size; (void)ws_size;
  const int*   idx   = (const int*)  d_in[0];
  const float* emb   = (const float*)d_in[1];
  const float* W_in  = (const float*)d_in[2];
  const float* convw = (const float*)d_in[3];
  const float* W_xp  = (const float*)d_in[4];
  const float* W_dt  = (const float*)d_in[5];
  const float* b_dt  = (const float*)d_in[6];
  const float* a_log = (const float*)d_in[7];
  const float* d_par = (const float*)d_in[8];
  const float* W_out = (const float*)d_in[9];
  const float* normw = (const float*)d_in[10];
  float* out = (float*)d_out;

  char* ws = (char*)d_ws;
  size_t off = 0;
  auto alloc = [&](size_t bytes) -> void* {
    void* p = ws + off;
    off += (bytes + 255) & ~(size_t)255;
    return p;
  };
  u16*   embbf  = (u16*)  alloc((size_t)VPAD * DMODEL * 2);
  u16*   winbf  = (u16*)  alloc((size_t)NLAYER * 2 * DINNER * DMODEL * 2);
  u16*   woutbf = (u16*)  alloc((size_t)NLAYER * DMODEL * DINNER * 2);
  float* xf     = (float*)alloc((size_t)MROWS * DMODEL * 4);
  u16*   xbf    = (u16*)  alloc((size_t)MROWS * DMODEL * 2);
  float* xz     = (float*)alloc((size_t)2 * MROWS * 2 * DINNER * 4);   // 2 split-K slices
  float* xs     = (float*)alloc((size_t)MROWS * DINNER * 4);
  float* dlt    = (float*)alloc((size_t)MROWS * DINNER * 4);
  float* bc     = (float*)alloc((size_t)MROWS * 2 * DSTATE * 4);
  u16*   ybf    = (u16*)  alloc((size_t)MROWS * DINNER * 2);
  u16*   xnbf   = (u16*)  alloc((size_t)MROWS * DMODEL * 2);
  float* part   = (float*)alloc((size_t)4 * MROWS * DMODEL * 4);

  prep_kern<<<2048, 256, 0, stream>>>(emb, W_in, W_out, idx, embbf, winbf, woutbf, xf, xbf);

  for (int l = 0; l < NLAYER; ++l) {
    // xz = x @ W_in^T, split-K x2 (384 blocks; partial slices xz[0], xz[XZS])
    gemm3_kern<false, true><<<dim3(8 * (2 * DINNER / 128), 1, 2), 256, 0, stream>>>(
        xbf, winbf + (size_t)l * 2 * DINNER * DMODEL, xz,
        MROWS, 2 * DINNER, DMODEL / 2, DMODEL, DMODEL);
    convxproj_kern<<<MROWS, 256, 0, stream>>>(
        xz, convw + (size_t)l * DINNER * DCONV,
        W_xp + (size_t)l * (2 * DSTATE + 1) * DINNER,
        W_dt + (size_t)l * DINNER, b_dt + (size_t)l * DINNER, xs, dlt, bc);
    scan_kern<<<BATCH * DINNER / 8, 256, 0, stream>>>(
        dlt, bc, xs, xz, a_log + (size_t)l * DINNER * DSTATE, d_par + (size_t)l * DINNER, ybf);
    gemm3_kern<false, true><<<dim3(8 * (DMODEL / 128), 1, 4), 256, 0, stream>>>(
        ybf, woutbf + (size_t)l * DMODEL * DINNER, part,
        MROWS, DMODEL, DINNER / 4, DINNER, DINNER);
    if (l < NLAYER - 1)
      redout_kern<<<MROWS * DMODEL / 4 / 256, 256, 0, stream>>>(part, xf, xbf);
  }
  rmsfuse_kern<<<MROWS, 256, 0, stream>>>(part, xf, normw, xnbf);
  gemm8_kern<<<4 * (VPAD / 256), 512, 0, stream>>>(
      xnbf, embbf, out, VV, DMODEL, DMODEL, DMODEL);
}